// Round 4
// baseline (778.382 us; speedup 1.0000x reference)
//
#include <hip/hip_runtime.h>
#include <stdint.h>

// Problem sizes.
static constexpr int Bn = 4096;
static constexpr int Dn = 5000;
static constexpr int Hn = 2000;
static constexpr int Ln = 50;
static constexpr int XW = 80;      // u64 words covering D (5120 bits >= 5000)
static constexpr int ZW = 32;      // u64 words covering H (2048 bits >= 2000)
static constexpr int Hpad = 2048;  // padded H (bit capacity)
static constexpr int Dpad = 5120;  // padded D = XW*64

__device__ __forceinline__ int popc_acc(uint64_t v, int acc) {
  // 2x v_and_b32 + 2x v_bcnt_u32_b32 (fused accumulate)
  acc = __builtin_popcount((uint32_t)v) + acc;
  acc = __builtin_popcount((uint32_t)(v >> 32)) + acc;
  return acc;
}
__device__ __forceinline__ int popc_acc2(uint32_t lo, uint32_t hi, int acc) {
  acc = __builtin_popcount(lo) + acc;
  acc = __builtin_popcount(hi) + acc;
  return acc;
}

// Pack x rows into TRANSPOSED bit matrix xbT[w][b]; 4 words per wave, coalesced reads.
__global__ void k_pack_x(const float* __restrict__ x, uint64_t* __restrict__ xbT) {
  int g = (int)((blockIdx.x * blockDim.x + threadIdx.x) >> 6);
  int lane = (int)(threadIdx.x & 63);
  constexpr int nq = XW >> 2;  // 20
  int row = g / nq;
  int q = g - row * nq;
  if (row >= Bn) return;
  int w0 = q << 2;
  unsigned long long m[4];
#pragma unroll
  for (int e = 0; e < 4; ++e) {
    int col = ((w0 + e) << 6) + lane;
    float v = (col < Dn) ? x[(size_t)row * Dn + col] : 0.0f;
    m[e] = __ballot(v >= 0.5f);
  }
  if (lane < 4) {
    unsigned long long mv = m[0];
    mv = (lane == 1) ? m[1] : mv;
    mv = (lane == 2) ? m[2] : mv;
    mv = (lane == 3) ? m[3] : mv;
    xbT[(size_t)(w0 + lane) * Bn + row] = mv;
  }
}

// One coalesced pass over W produces BOTH transposed row bitsets wbT[w][j]
// (ballot over d-lanes) and transposed column bitsets wtT[jw][d] (per-thread
// bit accumulation over 64 j-rows; coalesced store). Padding comes out zero.
__global__ __launch_bounds__(256) void k_pack_w(const float* __restrict__ W,
                                                uint64_t* __restrict__ wbT,
                                                uint64_t* __restrict__ wtT) {
  int d = (int)blockIdx.x * 256 + (int)threadIdx.x;  // 0..5119
  int j0 = (int)blockIdx.y * 64;                     // 0..1984 (Hpad/64 = 32 blocks)
  int lane = (int)(threadIdx.x & 63);
  int wv = (int)(threadIdx.x >> 6);                  // d-word sub-index in block
  uint64_t colbits = 0;
  for (int r = 0; r < 64; ++r) {
    int j = j0 + r;
    float v = (j < Hn && d < Dn) ? W[(size_t)j * Dn + d] : 0.0f;
    bool bit = v >= 0.5f;
    colbits |= ((uint64_t)(bit ? 1u : 0u)) << r;
    unsigned long long m = __ballot(bit);
    if (lane == 0) wbT[(size_t)(blockIdx.x * 4 + wv) * Hpad + j] = m;
  }
  wtT[(size_t)blockIdx.y * Dpad + d] = colbits;
}

// fwT[j][l] = sigmoid(2 * cw[l][j]), padded to 64 cols (pad = 0).
__global__ void k_pack_fwT(const float* __restrict__ cw, float* __restrict__ fwT) {
  int idx = blockIdx.x * blockDim.x + threadIdx.x;
  if (idx >= Hn * 64) return;
  int j = idx >> 6, l = idx & 63;
  float v = 0.0f;
  if (l < Ln) {
    float t = 2.0f * cw[(size_t)l * Hn + j];
    v = 1.0f / (1.0f + expf(-t));
  }
  fwT[idx] = v;
}

__global__ void k_zero(float* __restrict__ p, int n) {
  int i = blockIdx.x * blockDim.x + threadIdx.x;
  if (i < n) p[i] = 0.0f;
}

// Encoder: wave = 64 batch rows (per-lane) x 16 hidden units (per-SGPR stream).
// Per w: coalesced x word load (512B/wave) + 2 s_load_dwordx16 of weights +
// 64 VALU popcount-MACs. z stored as floats and as coalesced u16 bit groups.
__global__ __launch_bounds__(256) void k_enc(const uint64_t* __restrict__ xbT,
                                             const uint64_t* __restrict__ wbT,
                                             const float* __restrict__ b_enc,
                                             const float* __restrict__ act0b,
                                             float* __restrict__ z_out,
                                             uint16_t* __restrict__ zbT16) {
  int wv = __builtin_amdgcn_readfirstlane((int)threadIdx.x >> 6);
  int lane = (int)threadIdx.x & 63;
  int bg = (int)blockIdx.y;                 // 64 batch groups
  int jg = (int)blockIdx.x * 4 + wv;        // 128 j-groups of 16
  int b = (bg << 6) + lane;
  int j0 = jg << 4;

  int acc[16] = {};
  const uint64_t* xp = xbT + b;
#pragma unroll 2
  for (int w = 0; w < XW; ++w) {
    uint64_t xw = xp[(size_t)w * Bn];
    const uint64_t* wp = wbT + (size_t)w * Hpad + j0;  // uniform -> s_load
#pragma unroll
    for (int t = 0; t < 16; ++t) acc[t] = popc_acc(xw & wp[t], acc[t]);
  }

  uint32_t z16 = 0;
  if (j0 < Hn) {  // 2000 % 16 == 0: group fully valid or fully padded
    float zf[16];
#pragma unroll
    for (int t = 0; t < 16; ++t) {
      // exact: integer-valued acc (fp32-representable) + b_enc, then + act0_bias
      float h = ((float)acc[t] + b_enc[j0 + t]) + act0b[j0 + t];
      bool zb = (h >= 1.0f);
      z16 |= (zb ? (1u << t) : 0u);
      zf[t] = zb ? 1.0f : 0.0f;
    }
    float* zp = z_out + (size_t)b * Hn + j0;
#pragma unroll
    for (int q = 0; q < 4; ++q)
      *(float4*)(zp + 4 * q) =
          make_float4(zf[4 * q], zf[4 * q + 1], zf[4 * q + 2], zf[4 * q + 3]);
  }
  zbT16[(size_t)jg * Bn + b] = (uint16_t)z16;  // coalesced
}

// Decoder: wave = 64 batch rows (per-lane) x 32 outputs. The lane's full z row
// (2048 bits) is loaded ONCE into 64 u32 regs (coalesced u16 loads, fully
// static indexing), then weights stream through SGPRs: zero VMEM in hot loop.
__global__ __launch_bounds__(256) void k_dec(const uint16_t* __restrict__ zbT16,
                                             const uint64_t* __restrict__ wtT,
                                             const float* __restrict__ act3b,
                                             float* __restrict__ out) {
  int wv = __builtin_amdgcn_readfirstlane((int)threadIdx.x >> 6);
  int lane = (int)threadIdx.x & 63;
  int bg = (int)blockIdx.y;             // 64 batch groups
  int dc = (int)blockIdx.x * 4 + wv;    // 160 d-chunks of 32
  int b = (bg << 6) + lane;
  int dbase = dc << 5;

  uint32_t zr[64];
#pragma unroll
  for (int g = 0; g < 64; ++g) {
    uint32_t lo = zbT16[(size_t)(2 * g) * Bn + b];
    uint32_t hi = zbT16[(size_t)(2 * g + 1) * Bn + b];
    zr[g] = lo | (hi << 16);
  }

#pragma unroll
  for (int grp = 0; grp < 4; ++grp) {
    int d0 = dbase + grp * 8;
    int acc[8] = {};
    const uint64_t* tp0 = wtT + d0;
#pragma unroll
    for (int w = 0; w < ZW; ++w) {  // FULL unroll: zr indices stay static
      const uint64_t* tp = tp0 + (size_t)w * Dpad;  // uniform -> s_load
      uint32_t zlo = zr[2 * w], zhi = zr[2 * w + 1];
#pragma unroll
      for (int t = 0; t < 8; ++t) {
        uint64_t ww = tp[t];
        acc[t] = popc_acc2(zlo & (uint32_t)ww, zhi & (uint32_t)(ww >> 32), acc[t]);
      }
    }
    if (d0 < Dn) {  // 5000 % 8 == 0: group fully valid or fully padded
      float of[8];
#pragma unroll
      for (int t = 0; t < 8; ++t)
        of[t] = (((float)acc[t] + act3b[d0 + t]) >= 1.0f) ? 1.0f : 0.0f;
      float* op = out + (size_t)b * Dn + d0;
      *(float4*)op = make_float4(of[0], of[1], of[2], of[3]);
      *(float4*)(op + 4) = make_float4(of[4], of[5], of[6], of[7]);
    }
  }
}

// classification[b][l] = sum_j z[b][j] * fwT[j][l]; partials via atomicAdd.
__global__ __launch_bounds__(256) void k_cls(const float* __restrict__ z,
                                             const float* __restrict__ fwT,
                                             float* __restrict__ cls) {
  constexpr int TB = 4, JSPLIT = 16, CH = Hn / JSPLIT;  // 125
  int gw = (int)((blockIdx.x * blockDim.x + threadIdx.x) >> 6);
  int lane = (int)(threadIdx.x & 63);
  int bq = __builtin_amdgcn_readfirstlane(gw / JSPLIT);
  int jc = __builtin_amdgcn_readfirstlane(gw - bq * JSPLIT);
  int b0 = bq * TB;
  float acc[TB];
#pragma unroll
  for (int i = 0; i < TB; ++i) acc[i] = 0.0f;
  const float* zp = z + (size_t)b0 * Hn + (size_t)jc * CH;  // uniform -> scalar
  const float* fp = fwT + (size_t)jc * CH * 64 + lane;      // coalesced
#pragma unroll 5
  for (int t = 0; t < CH; ++t) {
    float fwv = fp[(size_t)t * 64];
#pragma unroll
    for (int i = 0; i < TB; ++i) acc[i] += zp[(size_t)i * Hn + t] * fwv;
  }
  if (lane < Ln) {
#pragma unroll
    for (int i = 0; i < TB; ++i)
      atomicAdd(&cls[(size_t)(b0 + i) * Ln + lane], acc[i]);
  }
}

extern "C" void kernel_launch(void* const* d_in, const int* in_sizes, int n_in,
                              void* d_out, int out_size, void* d_ws, size_t ws_size,
                              hipStream_t stream) {
  const float* x     = (const float*)d_in[0];  // [B][D]
  const float* W     = (const float*)d_in[1];  // [H][D]
  const float* b_enc = (const float*)d_in[2];  // [H]
  const float* act0b = (const float*)d_in[3];  // [H]
  const float* act3b = (const float*)d_in[4];  // [D]
  const float* cw    = (const float*)d_in[5];  // [L][H]

  float* out0 = (float*)d_out;              // output        [B][D]
  float* cls  = out0 + (size_t)Bn * Dn;     // classification[B][L]
  float* zout = cls + (size_t)Bn * Ln;      // z             [B][H]

  // Workspace (~6.8 MB).
  char* ws = (char*)d_ws;
  uint64_t* xbT   = (uint64_t*)ws; ws += (size_t)XW * Bn * 8;    // 2.62 MB [XW][Bn]
  uint64_t* wbT   = (uint64_t*)ws; ws += (size_t)XW * Hpad * 8;  // 1.31 MB [XW][Hpad]
  uint64_t* wtT   = (uint64_t*)ws; ws += (size_t)ZW * Dpad * 8;  // 1.31 MB [ZW][Dpad]
  uint16_t* zbT16 = (uint16_t*)ws; ws += (size_t)(Hpad / 16) * Bn * 2;  // 1.05 MB
  float*    fwT   = (float*)ws;    ws += (size_t)Hn * 64 * 4;    // 0.51 MB

  {  // x -> xbT (word-major transpose)
    long long waves = (long long)Bn * (XW / 4);
    k_pack_x<<<(int)((waves * 64 + 255) / 256), 256, 0, stream>>>(x, xbT);
  }
  {  // W -> wbT + wtT in one coalesced pass
    dim3 gw2(Dpad / 256, Hpad / 64);  // (20, 32)
    k_pack_w<<<gw2, 256, 0, stream>>>(W, wbT, wtT);
  }
  k_pack_fwT<<<(Hn * 64 + 255) / 256, 256, 0, stream>>>(cw, fwT);
  k_zero<<<(Bn * Ln + 255) / 256, 256, 0, stream>>>(cls, Bn * Ln);

  // enc: 64 bgroups x 128 jgroups = 8192 waves
  dim3 g1(32, 64);
  k_enc<<<g1, 256, 0, stream>>>(xbT, wbT, b_enc, act0b, zout, zbT16);

  {  // cls
    long long waves = (long long)(Bn / 4) * 16;
    k_cls<<<(int)((waves * 64 + 255) / 256), 256, 0, stream>>>(zout, fwT, cls);
  }

  // dec: 64 bgroups x 160 dchunks = 10240 waves
  dim3 g2(40, 64);
  k_dec<<<g2, 256, 0, stream>>>(zbT16, wtT, act3b, out0);
}

// Round 5
// 311.588 us; speedup vs baseline: 2.4981x; 2.4981x over previous
//
#include <hip/hip_runtime.h>
#include <stdint.h>

// Problem sizes.
static constexpr int Bn = 4096;
static constexpr int Dn = 5000;
static constexpr int Hn = 2000;
static constexpr int Ln = 50;
static constexpr int XW = 80;      // u64 words covering D (5120 bits >= 5000)
static constexpr int Hpad = 2048;  // padded H bit capacity (64 u32 chunks)
static constexpr int Dpad = 5120;  // padded D = XW*64

__device__ __forceinline__ int popc_acc(uint64_t v, int acc) {
  // 2x v_and_b32 + 2x v_bcnt_u32_b32 (fused accumulate)
  acc = __builtin_popcount((uint32_t)v) + acc;
  acc = __builtin_popcount((uint32_t)(v >> 32)) + acc;
  return acc;
}

// Pack x rows into TRANSPOSED bit matrix xbT[w][b]; 4 words per wave, coalesced reads.
__global__ void k_pack_x(const float* __restrict__ x, uint64_t* __restrict__ xbT) {
  int g = (int)((blockIdx.x * blockDim.x + threadIdx.x) >> 6);
  int lane = (int)(threadIdx.x & 63);
  constexpr int nq = XW >> 2;  // 20
  int row = g / nq;
  int q = g - row * nq;
  if (row >= Bn) return;
  int w0 = q << 2;
  unsigned long long m[4];
#pragma unroll
  for (int e = 0; e < 4; ++e) {
    int col = ((w0 + e) << 6) + lane;
    float v = (col < Dn) ? x[(size_t)row * Dn + col] : 0.0f;
    m[e] = __ballot(v >= 0.5f);
  }
  if (lane < 4) {
    unsigned long long mv = m[0];
    mv = (lane == 1) ? m[1] : mv;
    mv = (lane == 2) ? m[2] : mv;
    mv = (lane == 3) ? m[3] : mv;
    xbT[(size_t)(w0 + lane) * Bn + row] = mv;
  }
}

// One coalesced pass over W -> transposed row bitsets wbT[w][j] (u64, ballot over
// d-lanes) AND transposed column bitsets wt32[hw][d] (u32 over 32 j-rows each,
// per-thread bit accumulation, coalesced store). Padding comes out zero.
__global__ __launch_bounds__(256) void k_pack_w(const float* __restrict__ W,
                                                uint64_t* __restrict__ wbT,
                                                uint32_t* __restrict__ wt32) {
  int d = (int)blockIdx.x * 256 + (int)threadIdx.x;  // 0..5119
  int j0 = (int)blockIdx.y * 64;                     // 32 blocks of 64 j
  int lane = (int)(threadIdx.x & 63);
  int wv = (int)(threadIdx.x >> 6);                  // d-word sub-index in block
  uint64_t colbits = 0;
  for (int r = 0; r < 64; ++r) {
    int j = j0 + r;
    float v = (j < Hn && d < Dn) ? W[(size_t)j * Dn + d] : 0.0f;
    bool bit = v >= 0.5f;
    colbits |= ((uint64_t)(bit ? 1u : 0u)) << r;
    unsigned long long m = __ballot(bit);
    if (lane == 0) wbT[(size_t)(blockIdx.x * 4 + wv) * Hpad + j] = m;
  }
  wt32[(size_t)(blockIdx.y * 2) * Dpad + d] = (uint32_t)colbits;
  wt32[(size_t)(blockIdx.y * 2 + 1) * Dpad + d] = (uint32_t)(colbits >> 32);
}

// fwT[j][l] = sigmoid(2 * cw[l][j]), padded to 64 cols (pad = 0).
__global__ void k_pack_fwT(const float* __restrict__ cw, float* __restrict__ fwT) {
  int idx = blockIdx.x * blockDim.x + threadIdx.x;
  if (idx >= Hn * 64) return;
  int j = idx >> 6, l = idx & 63;
  float v = 0.0f;
  if (l < Ln) {
    float t = 2.0f * cw[(size_t)l * Hn + j];
    v = 1.0f / (1.0f + expf(-t));
  }
  fwT[idx] = v;
}

__global__ void k_zero(float* __restrict__ p, int n) {
  int i = blockIdx.x * blockDim.x + threadIdx.x;
  if (i < n) p[i] = 0.0f;
}

// Encoder: wave = 64 batch rows (per-lane) x 32 hidden units (SGPR weight stream).
// Per w-step: 1 coalesced x-word load (512B/wave) + 256B s_load of weights +
// 128 VALU popcount-MACs. Small state: acc[32] ints, no large live arrays.
// All 4 waves of a block share jg -> shared scalar-cache weight stream.
__global__ __launch_bounds__(256) void k_enc(const uint64_t* __restrict__ xbT,
                                             const uint64_t* __restrict__ wbT,
                                             const float* __restrict__ b_enc,
                                             const float* __restrict__ act0b,
                                             float* __restrict__ z_out,
                                             uint32_t* __restrict__ zb32) {
  int wv = __builtin_amdgcn_readfirstlane((int)threadIdx.x >> 6);
  int lane = (int)threadIdx.x & 63;
  int jg = (int)blockIdx.x;             // 0..63: j-group of 32
  int bg = (int)blockIdx.y * 4 + wv;    // 0..63: batch group of 64
  int b = (bg << 6) + lane;
  int j0 = jg << 5;

  int acc[32] = {};
  const uint64_t* xp = xbT + b;
  const uint64_t* wp0 = wbT + j0;
#pragma unroll 1
  for (int w = 0; w < XW; ++w) {
    uint64_t xw = xp[(size_t)w * Bn];
    const uint64_t* wp = wp0 + (size_t)w * Hpad;  // uniform -> s_load
#pragma unroll
    for (int t = 0; t < 32; ++t) acc[t] = popc_acc(xw & wp[t], acc[t]);
  }

  uint32_t z32 = 0;
  float zf[32];
#pragma unroll
  for (int t = 0; t < 32; ++t) {
    int j = j0 + t;
    int js = (j < Hn) ? j : (Hn - 1);
    // exact: integer-valued acc + b_enc, then + act0_bias (reference order)
    float h = ((float)acc[t] + b_enc[js]) + act0b[js];
    bool zb = (j < Hn) && (h >= 1.0f);
    z32 |= zb ? (1u << t) : 0u;
    zf[t] = zb ? 1.0f : 0.0f;
  }
  zb32[(size_t)jg * Bn + b] = z32;  // coalesced
  float* zp = z_out + (size_t)b * Hn + j0;
#pragma unroll
  for (int q = 0; q < 8; ++q)
    if (j0 + 4 * q < Hn)  // uniform; 2000 % 4 == 0
      *(float4*)(zp + 4 * q) =
          make_float4(zf[4 * q], zf[4 * q + 1], zf[4 * q + 2], zf[4 * q + 3]);
}

// Decoder: exact mirror of encoder. Wave = 64 batch rows x 32 outputs.
// Per hw-step: 1 coalesced z-word load (256B/wave) + 128B s_load of weight
// columns + 64 VALU popcount-MACs. acc[32] only -> high occupancy, no spills.
__global__ __launch_bounds__(256) void k_dec(const uint32_t* __restrict__ zb32,
                                             const uint32_t* __restrict__ wt32,
                                             const float* __restrict__ act3b,
                                             float* __restrict__ out) {
  int wv = __builtin_amdgcn_readfirstlane((int)threadIdx.x >> 6);
  int lane = (int)threadIdx.x & 63;
  int dc = (int)blockIdx.x;             // 0..159: d-chunk of 32
  int bg = (int)blockIdx.y * 4 + wv;    // 0..63
  int b = (bg << 6) + lane;
  int d0 = dc << 5;

  int acc[32] = {};
  const uint32_t* zp = zb32 + b;
  const uint32_t* tp0 = wt32 + d0;
#pragma unroll 1
  for (int hw = 0; hw < 64; ++hw) {
    uint32_t zw = zp[(size_t)hw * Bn];
    const uint32_t* tp = tp0 + (size_t)hw * Dpad;  // uniform -> s_load
#pragma unroll
    for (int t = 0; t < 32; ++t) acc[t] = __builtin_popcount(zw & tp[t]) + acc[t];
  }

  float of[32];
#pragma unroll
  for (int t = 0; t < 32; ++t) {
    int d = d0 + t;
    int ds = (d < Dn) ? d : (Dn - 1);
    of[t] = (((float)acc[t] + act3b[ds]) >= 1.0f) ? 1.0f : 0.0f;
  }
  float* op = out + (size_t)b * Dn + d0;
#pragma unroll
  for (int q = 0; q < 8; ++q)
    if (d0 + 4 * q < Dn)  // uniform; 5000 % 4 == 0
      *(float4*)(op + 4 * q) =
          make_float4(of[4 * q], of[4 * q + 1], of[4 * q + 2], of[4 * q + 3]);
}

// classification[b][l] = sum_j z[b][j] * fwT[j][l]; partials via atomicAdd.
__global__ __launch_bounds__(256) void k_cls(const float* __restrict__ z,
                                             const float* __restrict__ fwT,
                                             float* __restrict__ cls) {
  constexpr int TB = 4, JSPLIT = 16, CH = Hn / JSPLIT;  // 125
  int gw = (int)((blockIdx.x * blockDim.x + threadIdx.x) >> 6);
  int lane = (int)(threadIdx.x & 63);
  int bq = __builtin_amdgcn_readfirstlane(gw / JSPLIT);
  int jc = __builtin_amdgcn_readfirstlane(gw - bq * JSPLIT);
  int b0 = bq * TB;
  float acc[TB];
#pragma unroll
  for (int i = 0; i < TB; ++i) acc[i] = 0.0f;
  const float* zp = z + (size_t)b0 * Hn + (size_t)jc * CH;  // uniform -> scalar
  const float* fp = fwT + (size_t)jc * CH * 64 + lane;      // coalesced
#pragma unroll 5
  for (int t = 0; t < CH; ++t) {
    float fwv = fp[(size_t)t * 64];
#pragma unroll
    for (int i = 0; i < TB; ++i) acc[i] += zp[(size_t)i * Hn + t] * fwv;
  }
  if (lane < Ln) {
#pragma unroll
    for (int i = 0; i < TB; ++i)
      atomicAdd(&cls[(size_t)(b0 + i) * Ln + lane], acc[i]);
  }
}

extern "C" void kernel_launch(void* const* d_in, const int* in_sizes, int n_in,
                              void* d_out, int out_size, void* d_ws, size_t ws_size,
                              hipStream_t stream) {
  const float* x     = (const float*)d_in[0];  // [B][D]
  const float* W     = (const float*)d_in[1];  // [H][D]
  const float* b_enc = (const float*)d_in[2];  // [H]
  const float* act0b = (const float*)d_in[3];  // [H]
  const float* act3b = (const float*)d_in[4];  // [D]
  const float* cw    = (const float*)d_in[5];  // [L][H]

  float* out0 = (float*)d_out;              // output        [B][D]
  float* cls  = out0 + (size_t)Bn * Dn;     // classification[B][L]
  float* zout = cls + (size_t)Bn * Ln;      // z             [B][H]

  // Workspace (~6.8 MB).
  char* ws = (char*)d_ws;
  uint64_t* xbT  = (uint64_t*)ws; ws += (size_t)XW * Bn * 8;        // 2.62 MB [80][Bn]
  uint64_t* wbT  = (uint64_t*)ws; ws += (size_t)XW * Hpad * 8;      // 1.31 MB [80][Hpad]
  uint32_t* wt32 = (uint32_t*)ws; ws += (size_t)64 * Dpad * 4;      // 1.31 MB [64][Dpad]
  uint32_t* zb32 = (uint32_t*)ws; ws += (size_t)64 * Bn * 4;        // 1.05 MB [64][Bn]
  float*    fwT  = (float*)ws;    ws += (size_t)Hn * 64 * 4;        // 0.51 MB

  {  // x -> xbT (word-major transpose)
    long long waves = (long long)Bn * (XW / 4);
    k_pack_x<<<(int)((waves * 64 + 255) / 256), 256, 0, stream>>>(x, xbT);
  }
  {  // W -> wbT + wt32 in one coalesced pass
    dim3 gw2(Dpad / 256, Hpad / 64);  // (20, 32)
    k_pack_w<<<gw2, 256, 0, stream>>>(W, wbT, wt32);
  }
  k_pack_fwT<<<(Hn * 64 + 255) / 256, 256, 0, stream>>>(cw, fwT);
  k_zero<<<(Bn * Ln + 255) / 256, 256, 0, stream>>>(cls, Bn * Ln);

  // enc: 64 j-groups x 64 batch groups = 4096 waves (block shares jg)
  dim3 g1(64, 16);
  k_enc<<<g1, 256, 0, stream>>>(xbT, wbT, b_enc, act0b, zout, zb32);

  {  // cls
    long long waves = (long long)(Bn / 4) * 16;
    k_cls<<<(int)((waves * 64 + 255) / 256), 256, 0, stream>>>(zout, fwT, cls);
  }

  // dec: 160 d-chunks x 64 batch groups = 10240 waves (block shares dc)
  dim3 g2(160, 16);
  k_dec<<<g2, 256, 0, stream>>>(zb32, wt32, act3b, out0);
}

// Round 6
// 309.591 us; speedup vs baseline: 2.5142x; 1.0065x over previous
//
#include <hip/hip_runtime.h>
#include <stdint.h>

// Problem sizes.
static constexpr int Bn = 4096;
static constexpr int Dn = 5000;
static constexpr int Hn = 2000;
static constexpr int Ln = 50;
static constexpr int XW = 80;      // u64 words covering D (5120 bits >= 5000)
static constexpr int Hpad = 2048;  // padded H bit capacity (64 u32 chunks / 128 u16)
static constexpr int Dpad = 5120;  // padded D = XW*64

__device__ __forceinline__ int popc_acc(uint64_t v, int acc) {
  // 2x v_and_b32 + 2x v_bcnt_u32_b32 (fused accumulate)
  acc = __builtin_popcount((uint32_t)v) + acc;
  acc = __builtin_popcount((uint32_t)(v >> 32)) + acc;
  return acc;
}

// Pack x rows into word-PAIRED transposed bit matrix xb2[w2][b] (ulong2: words
// 2*w2, 2*w2+1) so the encoder loads 16B per 2 K-words. 4 words/wave, coalesced.
__global__ void k_pack_x(const float* __restrict__ x, uint64_t* __restrict__ xb2) {
  int g = (int)((blockIdx.x * blockDim.x + threadIdx.x) >> 6);
  int lane = (int)(threadIdx.x & 63);
  constexpr int nq = XW >> 2;  // 20
  int row = g / nq;
  int q = g - row * nq;
  if (row >= Bn) return;
  int w0 = q << 2;
  unsigned long long m[4];
#pragma unroll
  for (int e = 0; e < 4; ++e) {
    int col = ((w0 + e) << 6) + lane;
    float v = (col < Dn) ? x[(size_t)row * Dn + col] : 0.0f;
    m[e] = __ballot(v >= 0.5f);
  }
  if (lane < 4) {
    unsigned long long mv = m[0];
    mv = (lane == 1) ? m[1] : mv;
    mv = (lane == 2) ? m[2] : mv;
    mv = (lane == 3) ? m[3] : mv;
    int w = w0 + lane;
    // layout: [XW/2][Bn][2] u64
    xb2[((size_t)(w >> 1) * Bn + row) * 2 + (w & 1)] = mv;
  }
}

// One coalesced pass over W -> transposed row bitsets wbT[w][j] (u64, ballot over
// d-lanes) AND transposed column bitsets wt32[hw][d] (u32 over 32 j-rows each,
// per-thread bit accumulation, coalesced store). Padding comes out zero.
__global__ __launch_bounds__(256) void k_pack_w(const float* __restrict__ W,
                                                uint64_t* __restrict__ wbT,
                                                uint32_t* __restrict__ wt32) {
  int d = (int)blockIdx.x * 256 + (int)threadIdx.x;  // 0..5119
  int j0 = (int)blockIdx.y * 64;                     // 32 blocks of 64 j
  int lane = (int)(threadIdx.x & 63);
  int wv = (int)(threadIdx.x >> 6);                  // d-word sub-index in block
  uint64_t colbits = 0;
  for (int r = 0; r < 64; ++r) {
    int j = j0 + r;
    float v = (j < Hn && d < Dn) ? W[(size_t)j * Dn + d] : 0.0f;
    bool bit = v >= 0.5f;
    colbits |= ((uint64_t)(bit ? 1u : 0u)) << r;
    unsigned long long m = __ballot(bit);
    if (lane == 0) wbT[(size_t)(blockIdx.x * 4 + wv) * Hpad + j] = m;
  }
  wt32[(size_t)(blockIdx.y * 2) * Dpad + d] = (uint32_t)colbits;
  wt32[(size_t)(blockIdx.y * 2 + 1) * Dpad + d] = (uint32_t)(colbits >> 32);
}

// fwT[j][l] = sigmoid(2 * cw[l][j]), padded to 64 cols (pad = 0).
__global__ void k_pack_fwT(const float* __restrict__ cw, float* __restrict__ fwT) {
  int idx = blockIdx.x * blockDim.x + threadIdx.x;
  if (idx >= Hn * 64) return;
  int j = idx >> 6, l = idx & 63;
  float v = 0.0f;
  if (l < Ln) {
    float t = 2.0f * cw[(size_t)l * Hn + j];
    v = 1.0f / (1.0f + expf(-t));
  }
  fwT[idx] = v;
}

__global__ void k_zero(float* __restrict__ p, int n) {
  int i = blockIdx.x * blockDim.x + threadIdx.x;
  if (i < n) p[i] = 0.0f;
}

// Encoder: wave = 64 batch rows (per-lane) x 16 hidden units (SGPR weight stream).
// Per w2-iter: 1 coalesced dwordx4 x-load (2 K-words) + 256B s_load of weights +
// 128 VALU popcount-MACs. 8192 waves -> 8/SIMD launchable; 32-SGPR weight steps
// let the compiler keep multiple s_load steps in flight.
__global__ __launch_bounds__(256) void k_enc(const uint64_t* __restrict__ xb2,
                                             const uint64_t* __restrict__ wbT,
                                             const float* __restrict__ b_enc,
                                             const float* __restrict__ act0b,
                                             float* __restrict__ z_out,
                                             uint16_t* __restrict__ zb16) {
  int wv = __builtin_amdgcn_readfirstlane((int)threadIdx.x >> 6);
  int lane = (int)threadIdx.x & 63;
  int jg = (int)blockIdx.x;             // 0..127: j-group of 16
  int bg = (int)blockIdx.y * 4 + wv;    // 0..63: batch group of 64
  int b = (bg << 6) + lane;
  int j0 = jg << 4;

  int acc[16] = {};
  const uint64_t* xp = xb2 + 2 * b;  // [w2][Bn][2]
  const uint64_t* wp0 = wbT + j0;
#pragma unroll 2
  for (int w2 = 0; w2 < XW / 2; ++w2) {
    uint64_t x0 = xp[(size_t)w2 * (2 * Bn)];
    uint64_t x1 = xp[(size_t)w2 * (2 * Bn) + 1];
    const uint64_t* wpa = wp0 + (size_t)(2 * w2) * Hpad;      // uniform -> s_load
    const uint64_t* wpb = wp0 + (size_t)(2 * w2 + 1) * Hpad;  // uniform -> s_load
#pragma unroll
    for (int t = 0; t < 16; ++t) acc[t] = popc_acc(x0 & wpa[t], acc[t]);
#pragma unroll
    for (int t = 0; t < 16; ++t) acc[t] = popc_acc(x1 & wpb[t], acc[t]);
  }

  uint32_t z16 = 0;
  float zf[16];
#pragma unroll
  for (int t = 0; t < 16; ++t) {
    int j = j0 + t;
    int js = (j < Hn) ? j : (Hn - 1);
    // exact: integer-valued acc + b_enc, then + act0_bias (reference order)
    float h = ((float)acc[t] + b_enc[js]) + act0b[js];
    bool zb = (j < Hn) && (h >= 1.0f);
    z16 |= zb ? (1u << t) : 0u;
    zf[t] = zb ? 1.0f : 0.0f;
  }
  zb16[(size_t)jg * Bn + b] = (uint16_t)z16;  // u16 halves of dec's u32 chunks
  if (j0 < Hn) {  // 2000 % 16 == 0: group fully valid or fully padded
    float* zp = z_out + (size_t)b * Hn + j0;
#pragma unroll
    for (int q = 0; q < 4; ++q)
      *(float4*)(zp + 4 * q) =
          make_float4(zf[4 * q], zf[4 * q + 1], zf[4 * q + 2], zf[4 * q + 3]);
  }
}

// Decoder: wave = 64 batch rows x 32 outputs. Per hw-step: 1 coalesced z-word
// load (256B/wave) + 128B s_load of weight columns + 64 VALU popcount-MACs.
// unroll 2: two weight steps (64 SGPRs) in flight.
__global__ __launch_bounds__(256) void k_dec(const uint32_t* __restrict__ zb32,
                                             const uint32_t* __restrict__ wt32,
                                             const float* __restrict__ act3b,
                                             float* __restrict__ out) {
  int wv = __builtin_amdgcn_readfirstlane((int)threadIdx.x >> 6);
  int lane = (int)threadIdx.x & 63;
  int dc = (int)blockIdx.x;             // 0..159: d-chunk of 32
  int bg = (int)blockIdx.y * 4 + wv;    // 0..63
  int b = (bg << 6) + lane;
  int d0 = dc << 5;

  int acc[32] = {};
  const uint32_t* zp = zb32 + b;
  const uint32_t* tp0 = wt32 + d0;
#pragma unroll 2
  for (int hw = 0; hw < 64; ++hw) {
    uint32_t zw = zp[(size_t)hw * Bn];
    const uint32_t* tp = tp0 + (size_t)hw * Dpad;  // uniform -> s_load
#pragma unroll
    for (int t = 0; t < 32; ++t) acc[t] = __builtin_popcount(zw & tp[t]) + acc[t];
  }

  float of[32];
#pragma unroll
  for (int t = 0; t < 32; ++t) {
    int d = d0 + t;
    int ds = (d < Dn) ? d : (Dn - 1);
    of[t] = (((float)acc[t] + act3b[ds]) >= 1.0f) ? 1.0f : 0.0f;
  }
  float* op = out + (size_t)b * Dn + d0;
#pragma unroll
  for (int q = 0; q < 8; ++q)
    if (d0 + 4 * q < Dn)  // uniform; 5000 % 4 == 0
      *(float4*)(op + 4 * q) =
          make_float4(of[4 * q], of[4 * q + 1], of[4 * q + 2], of[4 * q + 3]);
}

// classification[b][l] = sum_j z[b][j] * fwT[j][l]; partials via atomicAdd.
__global__ __launch_bounds__(256) void k_cls(const float* __restrict__ z,
                                             const float* __restrict__ fwT,
                                             float* __restrict__ cls) {
  constexpr int TB = 4, JSPLIT = 16, CH = Hn / JSPLIT;  // 125
  int gw = (int)((blockIdx.x * blockDim.x + threadIdx.x) >> 6);
  int lane = (int)(threadIdx.x & 63);
  int bq = __builtin_amdgcn_readfirstlane(gw / JSPLIT);
  int jc = __builtin_amdgcn_readfirstlane(gw - bq * JSPLIT);
  int b0 = bq * TB;
  float acc[TB];
#pragma unroll
  for (int i = 0; i < TB; ++i) acc[i] = 0.0f;
  const float* zp = z + (size_t)b0 * Hn + (size_t)jc * CH;  // uniform -> scalar
  const float* fp = fwT + (size_t)jc * CH * 64 + lane;      // coalesced
#pragma unroll 5
  for (int t = 0; t < CH; ++t) {
    float fwv = fp[(size_t)t * 64];
#pragma unroll
    for (int i = 0; i < TB; ++i) acc[i] += zp[(size_t)i * Hn + t] * fwv;
  }
  if (lane < Ln) {
#pragma unroll
    for (int i = 0; i < TB; ++i)
      atomicAdd(&cls[(size_t)(b0 + i) * Ln + lane], acc[i]);
  }
}

extern "C" void kernel_launch(void* const* d_in, const int* in_sizes, int n_in,
                              void* d_out, int out_size, void* d_ws, size_t ws_size,
                              hipStream_t stream) {
  const float* x     = (const float*)d_in[0];  // [B][D]
  const float* W     = (const float*)d_in[1];  // [H][D]
  const float* b_enc = (const float*)d_in[2];  // [H]
  const float* act0b = (const float*)d_in[3];  // [H]
  const float* act3b = (const float*)d_in[4];  // [D]
  const float* cw    = (const float*)d_in[5];  // [L][H]

  float* out0 = (float*)d_out;              // output        [B][D]
  float* cls  = out0 + (size_t)Bn * Dn;     // classification[B][L]
  float* zout = cls + (size_t)Bn * Ln;      // z             [B][H]

  // Workspace (~6.8 MB).
  char* ws = (char*)d_ws;
  uint64_t* xb2  = (uint64_t*)ws; ws += (size_t)XW * Bn * 8;    // 2.62 MB [40][Bn][2]
  uint64_t* wbT  = (uint64_t*)ws; ws += (size_t)XW * Hpad * 8;  // 1.31 MB [80][Hpad]
  uint32_t* wt32 = (uint32_t*)ws; ws += (size_t)64 * Dpad * 4;  // 1.31 MB [64][Dpad]
  uint32_t* zb32 = (uint32_t*)ws; ws += (size_t)64 * Bn * 4;    // 1.05 MB [64][Bn] (=[128][Bn] u16)
  float*    fwT  = (float*)ws;    ws += (size_t)Hn * 64 * 4;    // 0.51 MB

  {  // x -> xb2 (paired word-major transpose)
    long long waves = (long long)Bn * (XW / 4);
    k_pack_x<<<(int)((waves * 64 + 255) / 256), 256, 0, stream>>>(x, xb2);
  }
  {  // W -> wbT + wt32 in one coalesced pass
    dim3 gw2(Dpad / 256, Hpad / 64);  // (20, 32)
    k_pack_w<<<gw2, 256, 0, stream>>>(W, wbT, wt32);
  }
  k_pack_fwT<<<(Hn * 64 + 255) / 256, 256, 0, stream>>>(cw, fwT);
  k_zero<<<(Bn * Ln + 255) / 256, 256, 0, stream>>>(cls, Bn * Ln);

  // enc: 128 j-groups x 64 batch groups = 8192 waves (block shares jg)
  dim3 g1(128, 16);
  k_enc<<<g1, 256, 0, stream>>>(xb2, wbT, b_enc, act0b, zout, (uint16_t*)zb32);

  {  // cls
    long long waves = (long long)(Bn / 4) * 16;
    k_cls<<<(int)((waves * 64 + 255) / 256), 256, 0, stream>>>(zout, fwT, cls);
  }

  // dec: 160 d-chunks x 64 batch groups = 10240 waves (block shares dc)
  dim3 g2(160, 16);
  k_dec<<<g2, 256, 0, stream>>>(zb32, wt32, act3b, out0);
}

// Round 7
// 298.398 us; speedup vs baseline: 2.6085x; 1.0375x over previous
//
#include <hip/hip_runtime.h>
#include <stdint.h>

// Problem sizes.
static constexpr int Bn = 4096;
static constexpr int Dn = 5000;
static constexpr int Hn = 2000;
static constexpr int Ln = 50;
static constexpr int XW = 80;      // u64 words covering D (5120 bits >= 5000)
static constexpr int Hpad = 2048;  // padded H bit capacity (64 u32 chunks / 128 u16)
static constexpr int Dpad = 5120;  // padded D = XW*64

__device__ __forceinline__ int popc_acc(uint64_t v, int acc) {
  // 2x v_and_b32 + 2x v_bcnt_u32_b32 (fused accumulate)
  acc = __builtin_popcount((uint32_t)v) + acc;
  acc = __builtin_popcount((uint32_t)(v >> 32)) + acc;
  return acc;
}

// Pack x rows into word-PAIRED transposed bit matrix xb2[w2][b][2] (ulong2) so the
// encoder loads 16B per 2 K-words. 4 words/wave, coalesced reads.
__global__ void k_pack_x(const float* __restrict__ x, uint64_t* __restrict__ xb2) {
  int g = (int)((blockIdx.x * blockDim.x + threadIdx.x) >> 6);
  int lane = (int)(threadIdx.x & 63);
  constexpr int nq = XW >> 2;  // 20
  int row = g / nq;
  int q = g - row * nq;
  if (row >= Bn) return;
  int w0 = q << 2;
  unsigned long long m[4];
#pragma unroll
  for (int e = 0; e < 4; ++e) {
    int col = ((w0 + e) << 6) + lane;
    float v = (col < Dn) ? x[(size_t)row * Dn + col] : 0.0f;
    m[e] = __ballot(v >= 0.5f);
  }
  if (lane < 4) {
    unsigned long long mv = m[0];
    mv = (lane == 1) ? m[1] : mv;
    mv = (lane == 2) ? m[2] : mv;
    mv = (lane == 3) ? m[3] : mv;
    int w = w0 + lane;
    xb2[((size_t)(w >> 1) * Bn + row) * 2 + (w & 1)] = mv;  // [XW/2][Bn][2]
  }
}

// One coalesced pass over W -> transposed row bitsets wbT[w][j] (u64, ballot over
// d-lanes) AND transposed column bitsets wt32[hw][d] (u32 over 32 j-rows each,
// per-thread bit accumulation, coalesced store). Padding comes out zero.
__global__ __launch_bounds__(256) void k_pack_w(const float* __restrict__ W,
                                                uint64_t* __restrict__ wbT,
                                                uint32_t* __restrict__ wt32) {
  int d = (int)blockIdx.x * 256 + (int)threadIdx.x;  // 0..5119
  int j0 = (int)blockIdx.y * 64;                     // 32 blocks of 64 j
  int lane = (int)(threadIdx.x & 63);
  int wv = (int)(threadIdx.x >> 6);                  // d-word sub-index in block
  uint64_t colbits = 0;
  for (int r = 0; r < 64; ++r) {
    int j = j0 + r;
    float v = (j < Hn && d < Dn) ? W[(size_t)j * Dn + d] : 0.0f;
    bool bit = v >= 0.5f;
    colbits |= ((uint64_t)(bit ? 1u : 0u)) << r;
    unsigned long long m = __ballot(bit);
    if (lane == 0) wbT[(size_t)(blockIdx.x * 4 + wv) * Hpad + j] = m;
  }
  wt32[(size_t)(blockIdx.y * 2) * Dpad + d] = (uint32_t)colbits;
  wt32[(size_t)(blockIdx.y * 2 + 1) * Dpad + d] = (uint32_t)(colbits >> 32);
}

// fwT[j][l] = sigmoid(2 * cw[l][j]), padded to 64 cols (pad = 0).
__global__ void k_pack_fwT(const float* __restrict__ cw, float* __restrict__ fwT) {
  int idx = blockIdx.x * blockDim.x + threadIdx.x;
  if (idx >= Hn * 64) return;
  int j = idx >> 6, l = idx & 63;
  float v = 0.0f;
  if (l < Ln) {
    float t = 2.0f * cw[(size_t)l * Hn + j];
    v = 1.0f / (1.0f + expf(-t));
  }
  fwT[idx] = v;
}

__global__ void k_zero(float* __restrict__ p, int n) {
  int i = blockIdx.x * blockDim.x + threadIdx.x;
  if (i < n) p[i] = 0.0f;
}

// Encoder: block stages its 16-j weight tile (80 w x 16 j u64 = 10KB) into LDS once;
// inner loop = per-lane coalesced x loads + broadcast ds_read_b128 weights +
// popcount MACs. No SGPR weight stream, no per-lane weight gathers.
__global__ __launch_bounds__(256) void k_enc(const uint64_t* __restrict__ xb2,
                                             const uint64_t* __restrict__ wbT,
                                             const float* __restrict__ b_enc,
                                             const float* __restrict__ act0b,
                                             float* __restrict__ z_out,
                                             uint16_t* __restrict__ zb16) {
  __shared__ uint64_t wl[XW][16];  // 10240 B
  int tid = (int)threadIdx.x;
  int jg = (int)blockIdx.x;  // 0..127: j-group of 16
  int j0 = jg << 4;
#pragma unroll
  for (int k = 0; k < 5; ++k) {
    int idx = k * 256 + tid;  // 0..1279
    int w = idx >> 4, j = idx & 15;
    wl[w][j] = wbT[(size_t)w * Hpad + j0 + j];
  }
  __syncthreads();

  int wv = __builtin_amdgcn_readfirstlane(tid >> 6);
  int lane = tid & 63;
  int bg = (int)blockIdx.y * 4 + wv;  // 0..63
  int b = (bg << 6) + lane;

  int acc[16] = {};
  const uint64_t* xp = xb2 + 2 * (size_t)b;
#pragma unroll 2
  for (int w2 = 0; w2 < XW / 2; ++w2) {
    const ulong2 xx = *(const ulong2*)(xp + (size_t)w2 * (2 * Bn));
#pragma unroll
    for (int t2 = 0; t2 < 8; ++t2) {
      ulong2 wa = *(ulong2*)&wl[2 * w2][2 * t2];      // broadcast ds_read_b128
      ulong2 wb = *(ulong2*)&wl[2 * w2 + 1][2 * t2];  // broadcast ds_read_b128
      acc[2 * t2]     = popc_acc(xx.x & wa.x, acc[2 * t2]);
      acc[2 * t2 + 1] = popc_acc(xx.x & wa.y, acc[2 * t2 + 1]);
      acc[2 * t2]     = popc_acc(xx.y & wb.x, acc[2 * t2]);
      acc[2 * t2 + 1] = popc_acc(xx.y & wb.y, acc[2 * t2 + 1]);
    }
  }

  uint32_t z16 = 0;
  float zf[16];
#pragma unroll
  for (int t = 0; t < 16; ++t) {
    int j = j0 + t;
    int js = (j < Hn) ? j : (Hn - 1);
    // exact: integer-valued acc + b_enc, then + act0_bias (reference order)
    float h = ((float)acc[t] + b_enc[js]) + act0b[js];
    bool zb = (j < Hn) && (h >= 1.0f);
    z16 |= zb ? (1u << t) : 0u;
    zf[t] = zb ? 1.0f : 0.0f;
  }
  // z bits land in [hw][Bn][2] u16 layout == u32 [hw][Bn] for the decoder.
  zb16[((size_t)(jg >> 1) * Bn + b) * 2 + (jg & 1)] = (uint16_t)z16;
  if (j0 < Hn) {  // 2000 % 16 == 0: group fully valid or fully padded
    float* zp = z_out + (size_t)b * Hn + j0;
#pragma unroll
    for (int q = 0; q < 4; ++q)
      *(float4*)(zp + 4 * q) =
          make_float4(zf[4 * q], zf[4 * q + 1], zf[4 * q + 2], zf[4 * q + 3]);
  }
}

// Decoder: block stages its 32-d weight-column tile (64 hw x 32 d u32 = 8KB) into
// LDS; inner loop = coalesced per-lane z-word load + broadcast ds_read_b128 +
// u32 popcount MACs.
__global__ __launch_bounds__(256) void k_dec(const uint32_t* __restrict__ zb32,
                                             const uint32_t* __restrict__ wt32,
                                             const float* __restrict__ act3b,
                                             float* __restrict__ out) {
  __shared__ uint32_t tl[64][32];  // 8192 B
  int tid = (int)threadIdx.x;
  int dc = (int)blockIdx.x;  // 0..159: d-chunk of 32
  int d0 = dc << 5;
#pragma unroll
  for (int k = 0; k < 8; ++k) {
    int idx = k * 256 + tid;  // 0..2047
    int hw = idx >> 5, dl = idx & 31;
    tl[hw][dl] = wt32[(size_t)hw * Dpad + d0 + dl];
  }
  __syncthreads();

  int wv = __builtin_amdgcn_readfirstlane(tid >> 6);
  int lane = tid & 63;
  int bg = (int)blockIdx.y * 4 + wv;  // 0..63
  int b = (bg << 6) + lane;

  int acc[32] = {};
  const uint32_t* zp = zb32 + b;
#pragma unroll 2
  for (int hw = 0; hw < 64; ++hw) {
    uint32_t zw = zp[(size_t)hw * Bn];  // coalesced 256B/wave
#pragma unroll
    for (int q = 0; q < 8; ++q) {
      uint4 w4 = *(uint4*)&tl[hw][q * 4];  // broadcast ds_read_b128
      acc[4 * q]     = __builtin_popcount(zw & w4.x) + acc[4 * q];
      acc[4 * q + 1] = __builtin_popcount(zw & w4.y) + acc[4 * q + 1];
      acc[4 * q + 2] = __builtin_popcount(zw & w4.z) + acc[4 * q + 2];
      acc[4 * q + 3] = __builtin_popcount(zw & w4.w) + acc[4 * q + 3];
    }
  }

  float of[32];
#pragma unroll
  for (int t = 0; t < 32; ++t) {
    int d = d0 + t;
    int ds = (d < Dn) ? d : (Dn - 1);
    of[t] = (((float)acc[t] + act3b[ds]) >= 1.0f) ? 1.0f : 0.0f;
  }
  float* op = out + (size_t)b * Dn + d0;
#pragma unroll
  for (int q = 0; q < 8; ++q)
    if (d0 + 4 * q < Dn)  // uniform; 5000 % 4 == 0
      *(float4*)(op + 4 * q) =
          make_float4(of[4 * q], of[4 * q + 1], of[4 * q + 2], of[4 * q + 3]);
}

// classification = z @ fwT: LDS-tiled outer-product GEMM.
// Block = 128 b-rows x 64 l x 256 j-slice (4 tiles of 64 j). Thread = 8b x 4l.
// Per jj: 3 broadcast-friendly ds_read_b128 + 32 FMA. atomicAdd finish (jsplit=8).
__global__ __launch_bounds__(256) void k_cls(const float* __restrict__ z,
                                             const float* __restrict__ fwT,
                                             float* __restrict__ cls) {
  __shared__ float zT[64][132];   // transposed z tile, padded stride (33 KB)
  __shared__ float fwL[64][64];   // fw tile (16 KB)
  int tid = (int)threadIdx.x;
  int bb0 = (int)blockIdx.x * 128;
  int jsp = (int)blockIdx.y;      // 0..7
  int tx = tid & 15, ty = tid >> 4;
  float acc[8][4] = {};

  for (int tile = 0; tile < 4; ++tile) {
    int jt0 = jsp * 256 + tile * 64;
    __syncthreads();
#pragma unroll
    for (int k = 0; k < 8; ++k) {
      int idx = k * 256 + tid;
      int r = idx >> 4, c4 = idx & 15;
      int j = jt0 + c4 * 4;
      float4 v = make_float4(0.f, 0.f, 0.f, 0.f);
      if (j < Hn) v = *(const float4*)(z + (size_t)(bb0 + r) * Hn + j);
      zT[c4 * 4 + 0][r] = v.x;
      zT[c4 * 4 + 1][r] = v.y;
      zT[c4 * 4 + 2][r] = v.z;
      zT[c4 * 4 + 3][r] = v.w;
    }
#pragma unroll
    for (int k = 0; k < 4; ++k) {
      int idx = k * 256 + tid;
      int jj = idx >> 4, c4 = idx & 15;
      int j = jt0 + jj;
      float4 v = make_float4(0.f, 0.f, 0.f, 0.f);
      if (j < Hn) v = *(const float4*)(fwT + (size_t)j * 64 + c4 * 4);
      *(float4*)&fwL[jj][c4 * 4] = v;
    }
    __syncthreads();
#pragma unroll 4
    for (int jj = 0; jj < 64; ++jj) {
      float4 fv = *(float4*)&fwL[jj][tx * 4];
      float4 za = *(float4*)&zT[jj][ty * 8];
      float4 zb = *(float4*)&zT[jj][ty * 8 + 4];
      float zz[8] = {za.x, za.y, za.z, za.w, zb.x, zb.y, zb.z, zb.w};
      float ff[4] = {fv.x, fv.y, fv.z, fv.w};
#pragma unroll
      for (int i = 0; i < 8; ++i)
#pragma unroll
        for (int l = 0; l < 4; ++l) acc[i][l] += zz[i] * ff[l];
    }
  }

#pragma unroll
  for (int i = 0; i < 8; ++i) {
    int b = bb0 + ty * 8 + i;
#pragma unroll
    for (int l = 0; l < 4; ++l) {
      int L = tx * 4 + l;
      if (L < Ln) atomicAdd(&cls[(size_t)b * Ln + L], acc[i][l]);
    }
  }
}

extern "C" void kernel_launch(void* const* d_in, const int* in_sizes, int n_in,
                              void* d_out, int out_size, void* d_ws, size_t ws_size,
                              hipStream_t stream) {
  const float* x     = (const float*)d_in[0];  // [B][D]
  const float* W     = (const float*)d_in[1];  // [H][D]
  const float* b_enc = (const float*)d_in[2];  // [H]
  const float* act0b = (const float*)d_in[3];  // [H]
  const float* act3b = (const float*)d_in[4];  // [D]
  const float* cw    = (const float*)d_in[5];  // [L][H]

  float* out0 = (float*)d_out;              // output        [B][D]
  float* cls  = out0 + (size_t)Bn * Dn;     // classification[B][L]
  float* zout = cls + (size_t)Bn * Ln;      // z             [B][H]

  // Workspace (~6.8 MB).
  char* ws = (char*)d_ws;
  uint64_t* xb2  = (uint64_t*)ws; ws += (size_t)XW * Bn * 8;    // 2.62 MB [40][Bn][2]
  uint64_t* wbT  = (uint64_t*)ws; ws += (size_t)XW * Hpad * 8;  // 1.31 MB [80][Hpad]
  uint32_t* wt32 = (uint32_t*)ws; ws += (size_t)64 * Dpad * 4;  // 1.31 MB [64][Dpad]
  uint32_t* zb32 = (uint32_t*)ws; ws += (size_t)64 * Bn * 4;    // 1.05 MB [64][Bn] u32 (=[hw][Bn][2] u16)
  float*    fwT  = (float*)ws;    ws += (size_t)Hn * 64 * 4;    // 0.51 MB

  {  // x -> xb2 (paired word-major transpose)
    long long waves = (long long)Bn * (XW / 4);
    k_pack_x<<<(int)((waves * 64 + 255) / 256), 256, 0, stream>>>(x, xb2);
  }
  {  // W -> wbT + wt32 in one coalesced pass
    dim3 gw2(Dpad / 256, Hpad / 64);  // (20, 32)
    k_pack_w<<<gw2, 256, 0, stream>>>(W, wbT, wt32);
  }
  k_pack_fwT<<<(Hn * 64 + 255) / 256, 256, 0, stream>>>(cw, fwT);
  k_zero<<<(Bn * Ln + 255) / 256, 256, 0, stream>>>(cls, Bn * Ln);

  // enc: 128 j-groups x 16 (4-wave batch quads) = 8192 waves
  dim3 g1(128, 16);
  k_enc<<<g1, 256, 0, stream>>>(xb2, wbT, b_enc, act0b, zout, (uint16_t*)zb32);

  // cls: 32 b-blocks x 8 j-splits = 256 blocks
  dim3 g3(32, 8);
  k_cls<<<g3, 256, 0, stream>>>(zout, fwT, cls);

  // dec: 160 d-chunks x 16 (4-wave batch quads) = 10240 waves
  dim3 g2(160, 16);
  k_dec<<<g2, 256, 0, stream>>>(zb32, wt32, act3b, out0);
}